// Round 11
// baseline (237.480 us; speedup 1.0000x reference)
//
#include <hip/hip_runtime.h>
#include <stdint.h>

#define B_ 8
#define N_ 8192
#define S_ 2048
#define D_ 256
#define BN_TOT (B_ * N_)   // 65536
#define SPLIT_ 8
#define SCH_ (S_ / SPLIT_) // 256
#define MAXH_ 12
#define NBLK_ (BN_TOT / 128) // 512 gemm blocks

typedef __attribute__((ext_vector_type(8))) short bf16x8;
typedef __attribute__((ext_vector_type(4))) float f32x4;

__device__ __forceinline__ float b2f(unsigned short u) {
  union { float f; uint32_t i; } v; v.i = ((uint32_t)u) << 16; return v.f;
}
__device__ __forceinline__ unsigned short f2b(float f) {
  union { float f; uint32_t i; } v; v.f = f;
  uint32_t r = v.i + 0x7FFF + ((v.i >> 16) & 1);
  return (unsigned short)(r >> 16);
}

__device__ __forceinline__ void gload_lds16(const void* g, void* l) {
  __builtin_amdgcn_global_load_lds(
      (const __attribute__((address_space(1))) void*)g,
      (__attribute__((address_space(3))) void*)l, 16, 0, 0);
}

// ---------------- small prep: weight casts + candidate pack ----------------
__global__ __launch_bounds__(256) void prep_small(
    const float* __restrict__ W0, const float* __restrict__ W1,
    const float* __restrict__ xyz2,
    unsigned short* __restrict__ w0b, unsigned short* __restrict__ w1b,
    float4* __restrict__ cand) {
  int bid = blockIdx.x;
  int t = threadIdx.x;
  if (bid < 512) {
    int i = bid * 256 + t;
    w0b[i] = f2b(W0[i]);
  } else if (bid < 768) {
    int i = (bid - 512) * 256 + t;
    w1b[i] = f2b(W1[i]);
  } else {
    int p = (bid - 768) * 256 + t;  // over B_*S_
    int b = p >> 11, s = p & (S_ - 1);
    const float* x2 = xyz2 + (size_t)b * 3 * S_;
    float x = x2[s], y = x2[S_ + s], z = x2[2 * S_ + s];
    double n2 = (double)x * x + (double)y * y + (double)z * z;
    cand[p] = make_float4(x, y, z, (float)(0.5 * n2));
  }
}

// ---------------- transpose-cast body (unchanged from proven prep2) ----------------
__device__ __forceinline__ void tc_body(
    const float* __restrict__ in, unsigned short* __restrict__ out,
    int L, int ldo, int bx, int by, int bz, int t, float (*lds)[33]) {
  int c0 = bx * 32;
  int r0 = by * 64;
  int tx = t & 31, ty = t >> 5;
  const float* src = in + ((size_t)bz * 256 + r0) * L + c0;
#pragma unroll
  for (int rr = 0; rr < 8; ++rr) {
    int r = ty + rr * 8;
    lds[r][tx] = src[(size_t)r * L + tx];
  }
  __syncthreads();
  int wr = t & 31;
  int wc = t >> 5;
#pragma unroll
  for (int it = 0; it < 4; ++it) {
    int cl = wc + it * 8;
    unsigned short a = f2b(lds[wr * 2][cl]);
    unsigned short b2 = f2b(lds[wr * 2 + 1][cl]);
    uint32_t packed = (uint32_t)a | ((uint32_t)b2 << 16);
    *(uint32_t*)&out[((size_t)bz * L + (c0 + cl)) * ldo + r0 + wr * 2] = packed;
  }
}

// ------- MEGA kernel: knn_split (VALU-bound) + transposes (HBM-bound), 1:5 interleave -------
// bid%6==0 -> knn block (2048 total); else transpose block (10240 total).
// Bodies are byte-identical to the R10-passing kernels; only dispatch mapping changed.
__global__ __launch_bounds__(256) void mega_kernel(
    const float* __restrict__ xyz1, const float4* __restrict__ cand,
    const float* __restrict__ points1, const float* __restrict__ points2,
    unsigned short* __restrict__ xcat, unsigned short* __restrict__ p2t,
    double4* __restrict__ Dp, int4* __restrict__ Ip) {
  __shared__ char smem[8448];  // max(knn hits 6144, transpose 64*33*4=8448)
  int bid = blockIdx.x;
  int t = threadIdx.x;

  if (bid % 6 != 0) {
    // ---------------- transpose path ----------------
    float(*lds)[33] = (float(*)[33])smem;
    int oid = (bid / 6) * 5 + (bid % 6) - 1;  // [0,10240)
    if (oid < 8192) {
      tc_body(points1, xcat, N_, 512, oid & 255, (oid >> 8) & 3, oid >> 10, t, lds);
    } else {
      int idx = oid - 8192;
      tc_body(points2, p2t, S_, 256, idx & 63, (idx >> 6) & 3, idx >> 8, t, lds);
    }
    return;
  }

  // ---------------- knn_split path (exact R3 structure, proven 65.7us) ----------------
  unsigned short* hits = (unsigned short*)smem;  // 256*MAXH_ entries
  int kid = bid / 6;                             // [0,2048)
  int b = (kid >> 5) & 7;
  int split = kid >> 8;
  int n = (kid & 31) * 256 + t;
  const float* x1 = xyz1 + (size_t)b * 3 * N_;
  float pxf = x1[n], pyf = x1[N_ + n], pzf = x1[2 * N_ + n];
  double px = pxf, py = pyf, pz = pzf;
  double n1 = px * px + py * py + pz * pz;
  float h = (float)(0.5 * n1);
  const float4* cb = cand + b * S_ + split * SCH_;

  // ---- pass 1: branchless fp32 top-3 values ----
  float d0 = 3.4e38f, d1 = 3.4e38f, d2 = 3.4e38f;
#pragma unroll 8
  for (int s = 0; s < SCH_; ++s) {
    float4 c = cb[s];  // wave-uniform -> scalar load
    float m = fmaf(-pzf, c.z, fmaf(-pyf, c.y, fmaf(-pxf, c.x, h + c.w)));
    float t1 = fmaxf(d0, m);
    d0 = fminf(d0, m);
    float t2 = fmaxf(d1, t1);
    d1 = fminf(d1, t1);
    d2 = fminf(d2, t2);
  }

  // ---- pass 2: record candidates below threshold ----
  float thr = d2 + 6e-4f;
  int cnt = 0;
  unsigned short* myh = hits + t * MAXH_;
#pragma unroll 4
  for (int s = 0; s < SCH_; ++s) {
    float4 c = cb[s];
    float m = fmaf(-pzf, c.z, fmaf(-pyf, c.y, fmaf(-pxf, c.x, h + c.w)));
    if (m < thr) {
      if (cnt < MAXH_) myh[cnt] = (unsigned short)s;
      cnt++;
    }
  }

  // ---- phase 3: fp64 confirm (exact ordering, tie-stable: ascending s, strict <) ----
  double e0 = 1e300, e1 = 1e300, e2 = 1e300;
  int i0 = 0, i1 = 0, i2 = 0;
#define INS_(dd, gs)                               \
  {                                                \
    bool c0 = dd < e0, c1 = dd < e1, c2 = dd < e2; \
    i2 = c1 ? i1 : (c2 ? gs : i2);                 \
    e2 = c1 ? e1 : (c2 ? dd : e2);                 \
    i1 = c0 ? i0 : (c1 ? gs : i1);                 \
    e1 = c0 ? e0 : (c1 ? dd : e1);                 \
    i0 = c0 ? gs : i0;                             \
    e0 = c0 ? dd : e0;                             \
  }
  if (cnt <= MAXH_) {
    for (int j = 0; j < cnt; ++j) {
      int s = myh[j];
      float4 c = cb[s];
      double cx = c.x, cy = c.y, cz = c.z;
      double dot64 = px * cx + py * cy + pz * cz;
      double n2 = cx * cx + cy * cy + cz * cz;
      double dd = (n1 + n2) - 2.0 * dot64;
      int gs = split * SCH_ + s;
      INS_(dd, gs);
    }
  } else {
    // overflow fallback (probability ~0): full fp64 scan of the chunk
    for (int s = 0; s < SCH_; ++s) {
      float4 c = cb[s];
      double cx = c.x, cy = c.y, cz = c.z;
      double dot64 = px * cx + py * cy + pz * cz;
      double n2 = cx * cx + cy * cy + cz * cz;
      double dd = (n1 + n2) - 2.0 * dot64;
      int gs = split * SCH_ + s;
      INS_(dd, gs);
    }
  }
#undef INS_
  int q = b * N_ + n;
  Dp[(size_t)split * BN_TOT + q] = make_double4(e0, e1, e2, 0.0);
  Ip[(size_t)split * BN_TOT + q] = make_int4(i0, i1, i2, 0);
}

// ---------------- merge split partials (exact fp64, tie-stable) ----------------
__global__ __launch_bounds__(256) void knn_merge(
    const double4* __restrict__ Dp, const int4* __restrict__ Ip,
    int4* __restrict__ knn_i, float4* __restrict__ knn_w) {
  int q = blockIdx.x * 256 + threadIdx.x;
  double d0 = 1e300, d1 = 1e300, d2 = 1e300;
  int i0 = 0, i1 = 0, i2 = 0;
#define INS_(dd, gs)                          \
  {                                           \
    bool c0 = dd < d0, c1 = dd < d1, c2 = dd < d2; \
    i2 = c1 ? i1 : (c2 ? gs : i2);            \
    d2 = c1 ? d1 : (c2 ? dd : d2);            \
    i1 = c0 ? i0 : (c1 ? gs : i1);            \
    d1 = c0 ? d0 : (c1 ? dd : d1);            \
    i0 = c0 ? gs : i0;                        \
    d0 = c0 ? dd : d0;                        \
  }
#pragma unroll
  for (int sp = 0; sp < SPLIT_; ++sp) {
    double4 D = Dp[(size_t)sp * BN_TOT + q];
    int4 I = Ip[(size_t)sp * BN_TOT + q];
    INS_(D.x, I.x);
    INS_(D.y, I.y);
    INS_(D.z, I.z);
  }
#undef INS_
  float f0 = (float)d0, f1 = (float)d1, f2 = (float)d2;
  float w0 = 1.0f / (f0 + 1e-8f), w1 = 1.0f / (f1 + 1e-8f), w2 = 1.0f / (f2 + 1e-8f);
  float inv = 1.0f / (w0 + w1 + w2);
  knn_i[q] = make_int4(i0, i1, i2, 0);
  knn_w[q] = make_float4(w0 * inv, w1 * inv, w2 * inv, 0.f);
}

// ---------------- gather-interpolate -> Xcat[:,256:512] ----------------
__global__ __launch_bounds__(256) void interp_kernel(
    const unsigned short* __restrict__ p2t, const int4* __restrict__ knn_i,
    const float4* __restrict__ knn_w, unsigned short* __restrict__ xcat) {
  int wid = threadIdx.x >> 6, lane = threadIdx.x & 63;
  int bn = blockIdx.x * 4 + wid;
  int b = bn >> 13;
  int4 ii = knn_i[bn];
  float4 ww = knn_w[bn];
  int d0 = lane * 4;
  const unsigned short* base = p2t + (size_t)b * S_ * 256;
  ushort4 v0 = *(const ushort4*)(base + (size_t)ii.x * 256 + d0);
  ushort4 v1 = *(const ushort4*)(base + (size_t)ii.y * 256 + d0);
  ushort4 v2 = *(const ushort4*)(base + (size_t)ii.z * 256 + d0);
  float r0 = ww.x * b2f(v0.x) + ww.y * b2f(v1.x) + ww.z * b2f(v2.x);
  float r1 = ww.x * b2f(v0.y) + ww.y * b2f(v1.y) + ww.z * b2f(v2.y);
  float r2 = ww.x * b2f(v0.z) + ww.y * b2f(v1.z) + ww.z * b2f(v2.z);
  float r3 = ww.x * b2f(v0.w) + ww.y * b2f(v1.w) + ww.z * b2f(v2.w);
  ushort4 o = make_ushort4(f2b(r0), f2b(r1), f2b(r2), f2b(r3));
  *(ushort4*)&xcat[(size_t)bn * 512 + 256 + d0] = o;
}

// ------- bf16 MFMA GEMM + fused BN-stats partials: C[M][256] = A[M][K]*Bt^T -------
// BN_A: if true, apply y = relu(v*scale[c]+shift[c]) to the A fragments in
// registers between ds_read and MFMA (channels c = ko + (lane>>4)*8 + j).
template <int K, bool BN_A>
__global__ __launch_bounds__(512) void gemm_bt(
    const unsigned short* __restrict__ A, const unsigned short* __restrict__ Bt,
    const float* __restrict__ scale, const float* __restrict__ shift,
    unsigned short* __restrict__ C, float* __restrict__ psq) {
  __shared__ unsigned short Alds[128 * 32];
  __shared__ unsigned short Blds[256 * 32];
  int t = threadIdx.x;
  int lane = t & 63, wid = t >> 6;
  int wr = wid >> 2, wc = wid & 3;
  size_t bm = (size_t)blockIdx.x * 128;

  f32x4 acc[4][4] = {};

  int akc = (t & 3) * 8;
  const unsigned short* aSrc = A + (bm + (t >> 2)) * K + akc;
  const unsigned short* bSrc1 = Bt + (size_t)(t >> 2) * K + akc;
  const unsigned short* bSrc2 = Bt + (size_t)((t >> 2) + 128) * K + akc;
  char* aDst = (char*)Alds + wid * 1024;
  char* bDst1 = (char*)Blds + wid * 1024;
  char* bDst2 = (char*)Blds + 8192 + wid * 1024;

  for (int kt = 0; kt < K / 32; ++kt) {
    int ko = kt * 32;
    gload_lds16(aSrc + ko, aDst);
    gload_lds16(bSrc1 + ko, bDst1);
    gload_lds16(bSrc2 + ko, bDst2);
    __syncthreads();
    bf16x8 a[4], bfr[4];
#pragma unroll
    for (int m = 0; m < 4; ++m) {
      int row = wr * 64 + m * 16 + (lane & 15);
      a[m] = *(const bf16x8*)&Alds[row * 32 + (lane >> 4) * 8];
    }
    if (BN_A) {
      int cb0 = ko + (lane >> 4) * 8;
      float4 s0 = *(const float4*)&scale[cb0];
      float4 s1 = *(const float4*)&scale[cb0 + 4];
      float4 h0 = *(const float4*)&shift[cb0];
      float4 h1 = *(const float4*)&shift[cb0 + 4];
      float sc[8] = {s0.x, s0.y, s0.z, s0.w, s1.x, s1.y, s1.z, s1.w};
      float sh[8] = {h0.x, h0.y, h0.z, h0.w, h1.x, h1.y, h1.z, h1.w};
#pragma unroll
      for (int m = 0; m < 4; ++m) {
        bf16x8 v = a[m];
#pragma unroll
        for (int j = 0; j < 8; ++j)
          v[j] = (short)f2b(fmaxf(b2f((unsigned short)v[j]) * sc[j] + sh[j], 0.f));
        a[m] = v;
      }
    }
#pragma unroll
    for (int n = 0; n < 4; ++n) {
      int col = wc * 64 + n * 16 + (lane & 15);
      bfr[n] = *(const bf16x8*)&Blds[col * 32 + (lane >> 4) * 8];
    }
#pragma unroll
    for (int m = 0; m < 4; ++m)
#pragma unroll
      for (int n = 0; n < 4; ++n)
        acc[m][n] = __builtin_amdgcn_mfma_f32_16x16x32_bf16(a[m], bfr[n], acc[m][n], 0, 0, 0);
    __syncthreads();
  }

  int crow0 = wr * 64 + (lane >> 4) * 4;
  int ccol0 = wc * 64 + (lane & 15);
#pragma unroll
  for (int m = 0; m < 4; ++m)
#pragma unroll
    for (int n = 0; n < 4; ++n)
#pragma unroll
      for (int j = 0; j < 4; ++j) {
        size_t r = bm + crow0 + m * 16 + j;
        C[r * 256 + ccol0 + n * 16] = f2b(acc[m][n][j]);
      }

  // fused BN-stats: per-block per-channel sum / sumsq of the fp32 acc.
  float* sqbuf = (float*)Alds;
  float cs[4], cq[4];
#pragma unroll
  for (int nn = 0; nn < 4; ++nn) {
    float s = 0.f, q = 0.f;
#pragma unroll
    for (int m = 0; m < 4; ++m)
#pragma unroll
      for (int j = 0; j < 4; ++j) {
        float v = acc[m][nn][j];
        s += v;
        q = fmaf(v, v, q);
      }
    s += __shfl_xor(s, 16);
    q += __shfl_xor(q, 16);
    s += __shfl_xor(s, 32);
    q += __shfl_xor(q, 32);
    cs[nn] = s;
    cq[nn] = q;
  }
  int colb = wc * 64 + (lane & 15);
  if (wr == 0 && lane < 16) {
#pragma unroll
    for (int nn = 0; nn < 4; ++nn) {
      sqbuf[(colb + nn * 16) * 2] = cs[nn];
      sqbuf[(colb + nn * 16) * 2 + 1] = cq[nn];
    }
  }
  __syncthreads();
  if (wr == 1 && lane < 16) {
#pragma unroll
    for (int nn = 0; nn < 4; ++nn) {
      int col = colb + nn * 16;
      psq[blockIdx.x * 512 + col * 2] = sqbuf[col * 2] + cs[nn];
      psq[blockIdx.x * 512 + col * 2 + 1] = sqbuf[col * 2 + 1] + cq[nn];
    }
  }
}

// ---------------- BN scale/shift from fused partials (16 blocks) ----------------
__global__ __launch_bounds__(256) void stats_final(
    const float* __restrict__ psq, const float* __restrict__ g,
    const float* __restrict__ be, float* __restrict__ scale,
    float* __restrict__ shift) {
  int t = threadIdx.x;
  int c = blockIdx.x * 16 + (t >> 4);
  int sub = t & 15;
  float s = 0.f, q = 0.f;
  for (int blk = sub; blk < NBLK_; blk += 16) {
    s += psq[blk * 512 + c * 2];
    q += psq[blk * 512 + c * 2 + 1];
  }
#pragma unroll
  for (int off = 8; off; off >>= 1) {
    s += __shfl_xor(s, off);
    q += __shfl_xor(q, off);
  }
  if (sub == 0) {
    float mean = s * (1.0f / 65536.0f);
    float var = fmaxf(q * (1.0f / 65536.0f) - mean * mean, 0.f);
    float sc = g[c] * rsqrtf(var + 1e-5f);
    scale[c] = sc;
    shift[c] = be[c] - mean * sc;
  }
}

// ------- final: BN+ReLU + transpose [bn][o] -> out f32 [B][256][N] -------
__global__ __launch_bounds__(256) void final_kernel(
    const unsigned short* __restrict__ Y1, const float* __restrict__ scale,
    const float* __restrict__ shift, float* __restrict__ out) {
  __shared__ float lds[32][65];
  int n0 = blockIdx.x * 32, o0 = blockIdx.y * 64, b = blockIdx.z;
  int t = threadIdx.x;
  int tx = t & 63, ty = t >> 6;
#pragma unroll
  for (int rr = 0; rr < 8; ++rr) {
    int nl = ty + rr * 4;
    lds[nl][tx] = b2f(Y1[((size_t)b * N_ + n0 + nl) * 256 + o0 + tx]);
  }
  __syncthreads();
  int wn = t & 31, wo = t >> 5;
#pragma unroll
  for (int it = 0; it < 8; ++it) {
    int ol = wo + it * 8;
    int o = o0 + ol;
    float v = fmaxf(lds[wn][ol] * scale[o] + shift[o], 0.f);
    out[((size_t)b * 256 + o) * N_ + n0 + wn] = v;
  }
}

// ---------------- workspace layout (bytes) ----------------
static const size_t OFF_XCAT = 0;                       // 67108864 (y1 aliases)
static const size_t OFF_P2T  = 67108864;                // 8388608
static const size_t OFF_KI   = 75497472;                // 1048576 (psq aliases after interp)
static const size_t OFF_KW   = 76546048;                // 1048576
static const size_t OFF_Y0   = 77594624;                // 33554432 (Dp/Ip alias)
static const size_t OFF_X1   = 111149056;               // 33554432 (cand aliases)
static const size_t OFF_W0B  = 144703488;               // 262144
static const size_t OFF_W1B  = 144965632;               // 131072
static const size_t OFF_SC0  = 145096704;               // 1024
static const size_t OFF_SH0  = OFF_SC0 + 1024;
static const size_t OFF_SC1  = OFF_SH0 + 1024;
static const size_t OFF_SH1  = OFF_SC1 + 1024;

extern "C" void kernel_launch(void* const* d_in, const int* in_sizes, int n_in,
                              void* d_out, int out_size, void* d_ws, size_t ws_size,
                              hipStream_t stream) {
  const float* xyz1    = (const float*)d_in[0];
  const float* xyz2    = (const float*)d_in[1];
  const float* points1 = (const float*)d_in[2];
  const float* points2 = (const float*)d_in[3];
  const float* W0      = (const float*)d_in[4];
  // d_in[5] = b0 (cancels exactly inside BatchNorm; skipped)
  const float* W1      = (const float*)d_in[6];
  // d_in[7] = b1 (cancels)
  const float* g0      = (const float*)d_in[8];
  const float* be0     = (const float*)d_in[9];
  const float* g1      = (const float*)d_in[10];
  const float* be1     = (const float*)d_in[11];

  char* ws = (char*)d_ws;
  unsigned short* xcat = (unsigned short*)(ws + OFF_XCAT);
  unsigned short* p2t  = (unsigned short*)(ws + OFF_P2T);
  int4*  ki  = (int4*)(ws + OFF_KI);
  float4* kw = (float4*)(ws + OFF_KW);
  unsigned short* y0  = (unsigned short*)(ws + OFF_Y0);
  unsigned short* y1  = (unsigned short*)(ws + OFF_XCAT);  // alias: xcat dead after GEMM0
  unsigned short* w0b = (unsigned short*)(ws + OFF_W0B);
  unsigned short* w1b = (unsigned short*)(ws + OFF_W1B);
  float* sc0 = (float*)(ws + OFF_SC0);
  float* sh0 = (float*)(ws + OFF_SH0);
  float* sc1 = (float*)(ws + OFF_SC1);
  float* sh1 = (float*)(ws + OFF_SH1);
  // aliases (regions dead at time of use):
  float4*  cand = (float4*)(ws + OFF_X1);   // only prep_small/mega use this region
  double4* Dp   = (double4*)(ws + OFF_Y0);  // dead before gemm0 writes y0
  int4*    Ip   = (int4*)(ws + OFF_Y0 + (size_t)SPLIT_ * BN_TOT * 32);
  float*   psq  = (float*)(ws + OFF_KI);    // ki dead after interp

  dim3 blk(256);

  prep_small<<<dim3(832), blk, 0, stream>>>(W0, W1, xyz2, w0b, w1b, cand);

  // knn (2048 blocks, VALU-bound) + transposes (10240 blocks, HBM-bound), interleaved 1:5
  mega_kernel<<<dim3(12288), blk, 0, stream>>>(xyz1, cand, points1, points2,
                                               xcat, p2t, Dp, Ip);

  knn_merge<<<dim3(BN_TOT / 256), blk, 0, stream>>>(Dp, Ip, ki, kw);

  interp_kernel<<<dim3(BN_TOT / 4), blk, 0, stream>>>(p2t, ki, kw, xcat);

  gemm_bt<512, false><<<dim3(NBLK_), dim3(512), 0, stream>>>(
      xcat, w0b, nullptr, nullptr, y0, psq);
  stats_final<<<dim3(16), blk, 0, stream>>>(psq, g0, be0, sc0, sh0);

  gemm_bt<256, true><<<dim3(NBLK_), dim3(512), 0, stream>>>(
      y0, w1b, sc0, sh0, y1, psq);
  stats_final<<<dim3(16), blk, 0, stream>>>(psq, g1, be1, sc1, sh1);

  final_kernel<<<dim3(N_ / 32, 4, B_), blk, 0, stream>>>(y1, sc1, sh1, (float*)d_out);
}

// Round 12
// 195.130 us; speedup vs baseline: 1.2170x; 1.2170x over previous
//
#include <hip/hip_runtime.h>
#include <stdint.h>

#define B_ 8
#define N_ 8192
#define S_ 2048
#define D_ 256
#define BN_TOT (B_ * N_)   // 65536
#define SPLIT_ 8
#define SCH_ (S_ / SPLIT_) // 256
#define MAXH_ 12
#define NBLK_ (BN_TOT / 128) // 512 gemm blocks

typedef __attribute__((ext_vector_type(8))) short bf16x8;
typedef __attribute__((ext_vector_type(4))) float f32x4;

__device__ __forceinline__ float b2f(unsigned short u) {
  union { float f; uint32_t i; } v; v.i = ((uint32_t)u) << 16; return v.f;
}
__device__ __forceinline__ unsigned short f2b(float f) {
  union { float f; uint32_t i; } v; v.f = f;
  uint32_t r = v.i + 0x7FFF + ((v.i >> 16) & 1);
  return (unsigned short)(r >> 16);
}

__device__ __forceinline__ void gload_lds16(const void* g, void* l) {
  __builtin_amdgcn_global_load_lds(
      (const __attribute__((address_space(1))) void*)g,
      (__attribute__((address_space(3))) void*)l, 16, 0, 0);
}

// ---------------- fused prep: transpose-casts + weight casts + candidate pack ----------------
__device__ __forceinline__ void tc_body(
    const float* __restrict__ in, unsigned short* __restrict__ out,
    int L, int ldo, int bx, int by, int bz, int t, float (*lds)[33]) {
  int c0 = bx * 32;
  int r0 = by * 64;
  int tx = t & 31, ty = t >> 5;
  const float* src = in + ((size_t)bz * 256 + r0) * L + c0;
#pragma unroll
  for (int rr = 0; rr < 8; ++rr) {
    int r = ty + rr * 8;
    lds[r][tx] = src[(size_t)r * L + tx];
  }
  __syncthreads();
  int wr = t & 31;
  int wc = t >> 5;
#pragma unroll
  for (int it = 0; it < 4; ++it) {
    int cl = wc + it * 8;
    unsigned short a = f2b(lds[wr * 2][cl]);
    unsigned short b2 = f2b(lds[wr * 2 + 1][cl]);
    uint32_t packed = (uint32_t)a | ((uint32_t)b2 << 16);
    *(uint32_t*)&out[((size_t)bz * L + (c0 + cl)) * ldo + r0 + wr * 2] = packed;
  }
}

__global__ __launch_bounds__(256) void prep2_kernel(
    const float* __restrict__ points1, const float* __restrict__ points2,
    const float* __restrict__ W0, const float* __restrict__ W1,
    const float* __restrict__ xyz2,
    unsigned short* __restrict__ xcat, unsigned short* __restrict__ p2t,
    unsigned short* __restrict__ w0b, unsigned short* __restrict__ w1b,
    float4* __restrict__ cand) {
  __shared__ float lds[64][33];
  int bid = blockIdx.x;
  int t = threadIdx.x;
  if (bid < 8192) {
    tc_body(points1, xcat, N_, 512, bid & 255, (bid >> 8) & 3, bid >> 10, t, lds);
  } else if (bid < 10240) {
    int idx = bid - 8192;
    tc_body(points2, p2t, S_, 256, idx & 63, (idx >> 6) & 3, idx >> 8, t, lds);
  } else {
    int r = bid - 10240;
    if (r < 512) {
      int i = r * 256 + t;
      w0b[i] = f2b(W0[i]);
    } else if (r < 768) {
      int i = (r - 512) * 256 + t;
      w1b[i] = f2b(W1[i]);
    } else {
      int p = (r - 768) * 256 + t;  // over B_*S_
      int b = p >> 11, s = p & (S_ - 1);
      const float* x2 = xyz2 + (size_t)b * 3 * S_;
      float x = x2[s], y = x2[S_ + s], z = x2[2 * S_ + s];
      double n2 = (double)x * x + (double)y * y + (double)z * z;
      cand[p] = make_float4(x, y, z, (float)(0.5 * n2));
    }
  }
}

// ---------------- 3-NN split pass (R3 structure; now emits INDICES ONLY) ----------------
// Pass 1: branchless fp32 top-3 VALUES (m = d/2 scale) via min/max network.
// Pass 2: record s with m < d2 + 6e-4 to per-lane LDS list (err bound ~5e-5).
// Phase 3: fp64-exact confirm+order; output top-3 global indices (ushort, S<65536).
// knn_merge recomputes the identical fp64 distances from xyz1/cand.
__global__ __launch_bounds__(256) void knn_split(
    const float* __restrict__ xyz1, const float4* __restrict__ cand,
    ushort4* __restrict__ Ip) {
  __shared__ unsigned short hits[256 * MAXH_];
  int b = blockIdx.y;
  int split = blockIdx.z;
  int n = blockIdx.x * 256 + threadIdx.x;
  const float* x1 = xyz1 + (size_t)b * 3 * N_;
  float pxf = x1[n], pyf = x1[N_ + n], pzf = x1[2 * N_ + n];
  double px = pxf, py = pyf, pz = pzf;
  double n1 = px * px + py * py + pz * pz;
  float h = (float)(0.5 * n1);
  const float4* cb = cand + b * S_ + split * SCH_;

  // ---- pass 1: branchless fp32 top-3 values ----
  float d0 = 3.4e38f, d1 = 3.4e38f, d2 = 3.4e38f;
#pragma unroll 8
  for (int s = 0; s < SCH_; ++s) {
    float4 c = cb[s];  // wave-uniform -> scalar load
    float m = fmaf(-pzf, c.z, fmaf(-pyf, c.y, fmaf(-pxf, c.x, h + c.w)));
    float t1 = fmaxf(d0, m);
    d0 = fminf(d0, m);
    float t2 = fmaxf(d1, t1);
    d1 = fminf(d1, t1);
    d2 = fminf(d2, t2);
  }

  // ---- pass 2: record candidates below threshold ----
  float thr = d2 + 6e-4f;
  int cnt = 0;
  unsigned short* myh = hits + threadIdx.x * MAXH_;
#pragma unroll 4
  for (int s = 0; s < SCH_; ++s) {
    float4 c = cb[s];
    float m = fmaf(-pzf, c.z, fmaf(-pyf, c.y, fmaf(-pxf, c.x, h + c.w)));
    if (m < thr) {
      if (cnt < MAXH_) myh[cnt] = (unsigned short)s;
      cnt++;
    }
  }

  // ---- phase 3: fp64 confirm (exact ordering, tie-stable: ascending s, strict <) ----
  double e0 = 1e300, e1 = 1e300, e2 = 1e300;
  int i0 = 0, i1 = 0, i2 = 0;
#define INS_(dd, gs)                               \
  {                                                \
    bool c0 = dd < e0, c1 = dd < e1, c2 = dd < e2; \
    i2 = c1 ? i1 : (c2 ? gs : i2);                 \
    e2 = c1 ? e1 : (c2 ? dd : e2);                 \
    i1 = c0 ? i0 : (c1 ? gs : i1);                 \
    e1 = c0 ? e0 : (c1 ? dd : e1);                 \
    i0 = c0 ? gs : i0;                             \
    e0 = c0 ? dd : e0;                             \
  }
  if (cnt <= MAXH_) {
    for (int j = 0; j < cnt; ++j) {
      int s = myh[j];
      float4 c = cb[s];
      double cx = c.x, cy = c.y, cz = c.z;
      double dot64 = px * cx + py * cy + pz * cz;
      double n2 = cx * cx + cy * cy + cz * cz;
      double dd = (n1 + n2) - 2.0 * dot64;
      int gs = split * SCH_ + s;
      INS_(dd, gs);
    }
  } else {
    // overflow fallback (probability ~0): full fp64 scan of the chunk
    for (int s = 0; s < SCH_; ++s) {
      float4 c = cb[s];
      double cx = c.x, cy = c.y, cz = c.z;
      double dot64 = px * cx + py * cy + pz * cz;
      double n2 = cx * cx + cy * cy + cz * cz;
      double dd = (n1 + n2) - 2.0 * dot64;
      int gs = split * SCH_ + s;
      INS_(dd, gs);
    }
  }
#undef INS_
  int q = b * N_ + n;
  Ip[(size_t)split * BN_TOT + q] =
      make_ushort4((unsigned short)i0, (unsigned short)i1, (unsigned short)i2, 0);
}

// ------- merge: recompute fp64 dist from indices (identical expression), tie-stable -------
__global__ __launch_bounds__(256) void knn_merge(
    const float* __restrict__ xyz1, const float4* __restrict__ cand,
    const ushort4* __restrict__ Ip,
    int4* __restrict__ knn_i, float4* __restrict__ knn_w) {
  int q = blockIdx.x * 256 + threadIdx.x;
  int b = q >> 13;
  int n = q & (N_ - 1);
  const float* x1 = xyz1 + (size_t)b * 3 * N_;
  double px = x1[n], py = x1[N_ + n], pz = x1[2 * N_ + n];
  double n1 = px * px + py * py + pz * pz;
  const float4* cb = cand + b * S_;
  double d0 = 1e300, d1 = 1e300, d2 = 1e300;
  int i0 = 0, i1 = 0, i2 = 0;
#define INS_(gs)                                   \
  {                                                \
    float4 c = cb[gs];                             \
    double cx = c.x, cy = c.y, cz = c.z;           \
    double dot64 = px * cx + py * cy + pz * cz;    \
    double n2 = cx * cx + cy * cy + cz * cz;       \
    double dd = (n1 + n2) - 2.0 * dot64;           \
    bool c0 = dd < d0, c1 = dd < d1, c2 = dd < d2; \
    i2 = c1 ? i1 : (c2 ? (int)(gs) : i2);          \
    d2 = c1 ? d1 : (c2 ? dd : d2);                 \
    i1 = c0 ? i0 : (c1 ? (int)(gs) : i1);          \
    d1 = c0 ? d0 : (c1 ? dd : d1);                 \
    i0 = c0 ? (int)(gs) : i0;                      \
    d0 = c0 ? dd : d0;                             \
  }
#pragma unroll
  for (int sp = 0; sp < SPLIT_; ++sp) {
    ushort4 I = Ip[(size_t)sp * BN_TOT + q];
    INS_(I.x);
    INS_(I.y);
    INS_(I.z);
  }
#undef INS_
  float f0 = (float)d0, f1 = (float)d1, f2 = (float)d2;
  float w0 = 1.0f / (f0 + 1e-8f), w1 = 1.0f / (f1 + 1e-8f), w2 = 1.0f / (f2 + 1e-8f);
  float inv = 1.0f / (w0 + w1 + w2);
  knn_i[q] = make_int4(i0, i1, i2, 0);
  knn_w[q] = make_float4(w0 * inv, w1 * inv, w2 * inv, 0.f);
}

// ---------------- gather-interpolate -> Xcat[:,256:512] ----------------
__global__ __launch_bounds__(256) void interp_kernel(
    const unsigned short* __restrict__ p2t, const int4* __restrict__ knn_i,
    const float4* __restrict__ knn_w, unsigned short* __restrict__ xcat) {
  int wid = threadIdx.x >> 6, lane = threadIdx.x & 63;
  int bn = blockIdx.x * 4 + wid;
  int b = bn >> 13;
  int4 ii = knn_i[bn];
  float4 ww = knn_w[bn];
  int d0 = lane * 4;
  const unsigned short* base = p2t + (size_t)b * S_ * 256;
  ushort4 v0 = *(const ushort4*)(base + (size_t)ii.x * 256 + d0);
  ushort4 v1 = *(const ushort4*)(base + (size_t)ii.y * 256 + d0);
  ushort4 v2 = *(const ushort4*)(base + (size_t)ii.z * 256 + d0);
  float r0 = ww.x * b2f(v0.x) + ww.y * b2f(v1.x) + ww.z * b2f(v2.x);
  float r1 = ww.x * b2f(v0.y) + ww.y * b2f(v1.y) + ww.z * b2f(v2.y);
  float r2 = ww.x * b2f(v0.z) + ww.y * b2f(v1.z) + ww.z * b2f(v2.z);
  float r3 = ww.x * b2f(v0.w) + ww.y * b2f(v1.w) + ww.z * b2f(v2.w);
  ushort4 o = make_ushort4(f2b(r0), f2b(r1), f2b(r2), f2b(r3));
  *(ushort4*)&xcat[(size_t)bn * 512 + 256 + d0] = o;
}

// ------- bf16 MFMA GEMM + fused BN-stats partials: C[M][256] = A[M][K]*Bt^T -------
// BN_A: if true, apply y = relu(v*scale[c]+shift[c]) to the A fragments in
// registers between ds_read and MFMA (channels c = ko + (lane>>4)*8 + j).
template <int K, bool BN_A>
__global__ __launch_bounds__(512) void gemm_bt(
    const unsigned short* __restrict__ A, const unsigned short* __restrict__ Bt,
    const float* __restrict__ scale, const float* __restrict__ shift,
    unsigned short* __restrict__ C, float* __restrict__ psq) {
  __shared__ unsigned short Alds[128 * 32];
  __shared__ unsigned short Blds[256 * 32];
  int t = threadIdx.x;
  int lane = t & 63, wid = t >> 6;
  int wr = wid >> 2, wc = wid & 3;
  size_t bm = (size_t)blockIdx.x * 128;

  f32x4 acc[4][4] = {};

  int akc = (t & 3) * 8;
  const unsigned short* aSrc = A + (bm + (t >> 2)) * K + akc;
  const unsigned short* bSrc1 = Bt + (size_t)(t >> 2) * K + akc;
  const unsigned short* bSrc2 = Bt + (size_t)((t >> 2) + 128) * K + akc;
  char* aDst = (char*)Alds + wid * 1024;
  char* bDst1 = (char*)Blds + wid * 1024;
  char* bDst2 = (char*)Blds + 8192 + wid * 1024;

  for (int kt = 0; kt < K / 32; ++kt) {
    int ko = kt * 32;
    gload_lds16(aSrc + ko, aDst);
    gload_lds16(bSrc1 + ko, bDst1);
    gload_lds16(bSrc2 + ko, bDst2);
    __syncthreads();
    bf16x8 a[4], bfr[4];
#pragma unroll
    for (int m = 0; m < 4; ++m) {
      int row = wr * 64 + m * 16 + (lane & 15);
      a[m] = *(const bf16x8*)&Alds[row * 32 + (lane >> 4) * 8];
    }
    if (BN_A) {
      int cb0 = ko + (lane >> 4) * 8;
      float4 s0 = *(const float4*)&scale[cb0];
      float4 s1 = *(const float4*)&scale[cb0 + 4];
      float4 h0 = *(const float4*)&shift[cb0];
      float4 h1 = *(const float4*)&shift[cb0 + 4];
      float sc[8] = {s0.x, s0.y, s0.z, s0.w, s1.x, s1.y, s1.z, s1.w};
      float sh[8] = {h0.x, h0.y, h0.z, h0.w, h1.x, h1.y, h1.z, h1.w};
#pragma unroll
      for (int m = 0; m < 4; ++m) {
        bf16x8 v = a[m];
#pragma unroll
        for (int j = 0; j < 8; ++j)
          v[j] = (short)f2b(fmaxf(b2f((unsigned short)v[j]) * sc[j] + sh[j], 0.f));
        a[m] = v;
      }
    }
#pragma unroll
    for (int n = 0; n < 4; ++n) {
      int col = wc * 64 + n * 16 + (lane & 15);
      bfr[n] = *(const bf16x8*)&Blds[col * 32 + (lane >> 4) * 8];
    }
#pragma unroll
    for (int m = 0; m < 4; ++m)
#pragma unroll
      for (int n = 0; n < 4; ++n)
        acc[m][n] = __builtin_amdgcn_mfma_f32_16x16x32_bf16(a[m], bfr[n], acc[m][n], 0, 0, 0);
    __syncthreads();
  }

  int crow0 = wr * 64 + (lane >> 4) * 4;
  int ccol0 = wc * 64 + (lane & 15);
#pragma unroll
  for (int m = 0; m < 4; ++m)
#pragma unroll
    for (int n = 0; n < 4; ++n)
#pragma unroll
      for (int j = 0; j < 4; ++j) {
        size_t r = bm + crow0 + m * 16 + j;
        C[r * 256 + ccol0 + n * 16] = f2b(acc[m][n][j]);
      }

  // fused BN-stats: per-block per-channel sum / sumsq of the fp32 acc.
  float* sqbuf = (float*)Alds;
  float cs[4], cq[4];
#pragma unroll
  for (int nn = 0; nn < 4; ++nn) {
    float s = 0.f, q = 0.f;
#pragma unroll
    for (int m = 0; m < 4; ++m)
#pragma unroll
      for (int j = 0; j < 4; ++j) {
        float v = acc[m][nn][j];
        s += v;
        q = fmaf(v, v, q);
      }
    s += __shfl_xor(s, 16);
    q += __shfl_xor(q, 16);
    s += __shfl_xor(s, 32);
    q += __shfl_xor(q, 32);
    cs[nn] = s;
    cq[nn] = q;
  }
  int colb = wc * 64 + (lane & 15);
  if (wr == 0 && lane < 16) {
#pragma unroll
    for (int nn = 0; nn < 4; ++nn) {
      sqbuf[(colb + nn * 16) * 2] = cs[nn];
      sqbuf[(colb + nn * 16) * 2 + 1] = cq[nn];
    }
  }
  __syncthreads();
  if (wr == 1 && lane < 16) {
#pragma unroll
    for (int nn = 0; nn < 4; ++nn) {
      int col = colb + nn * 16;
      psq[blockIdx.x * 512 + col * 2] = sqbuf[col * 2] + cs[nn];
      psq[blockIdx.x * 512 + col * 2 + 1] = sqbuf[col * 2 + 1] + cq[nn];
    }
  }
}

// ---------------- BN scale/shift from fused partials (16 blocks) ----------------
__global__ __launch_bounds__(256) void stats_final(
    const float* __restrict__ psq, const float* __restrict__ g,
    const float* __restrict__ be, float* __restrict__ scale,
    float* __restrict__ shift) {
  int t = threadIdx.x;
  int c = blockIdx.x * 16 + (t >> 4);
  int sub = t & 15;
  float s = 0.f, q = 0.f;
  for (int blk = sub; blk < NBLK_; blk += 16) {
    s += psq[blk * 512 + c * 2];
    q += psq[blk * 512 + c * 2 + 1];
  }
#pragma unroll
  for (int off = 8; off; off >>= 1) {
    s += __shfl_xor(s, off);
    q += __shfl_xor(q, off);
  }
  if (sub == 0) {
    float mean = s * (1.0f / 65536.0f);
    float var = fmaxf(q * (1.0f / 65536.0f) - mean * mean, 0.f);
    float sc = g[c] * rsqrtf(var + 1e-5f);
    scale[c] = sc;
    shift[c] = be[c] - mean * sc;
  }
}

// ------- final: BN+ReLU + transpose [bn][o] -> out f32 [B][256][N] -------
__global__ __launch_bounds__(256) void final_kernel(
    const unsigned short* __restrict__ Y1, const float* __restrict__ scale,
    const float* __restrict__ shift, float* __restrict__ out) {
  __shared__ float lds[32][65];
  int n0 = blockIdx.x * 32, o0 = blockIdx.y * 64, b = blockIdx.z;
  int t = threadIdx.x;
  int tx = t & 63, ty = t >> 6;
#pragma unroll
  for (int rr = 0; rr < 8; ++rr) {
    int nl = ty + rr * 4;
    lds[nl][tx] = b2f(Y1[((size_t)b * N_ + n0 + nl) * 256 + o0 + tx]);
  }
  __syncthreads();
  int wn = t & 31, wo = t >> 5;
#pragma unroll
  for (int it = 0; it < 8; ++it) {
    int ol = wo + it * 8;
    int o = o0 + ol;
    float v = fmaxf(lds[wn][ol] * scale[o] + shift[o], 0.f);
    out[((size_t)b * 256 + o) * N_ + n0 + wn] = v;
  }
}

// ---------------- workspace layout (bytes) ----------------
static const size_t OFF_XCAT = 0;                       // 67108864 (y1 aliases)
static const size_t OFF_P2T  = 67108864;                // 8388608
static const size_t OFF_KI   = 75497472;                // 1048576 (psq aliases after interp)
static const size_t OFF_KW   = 76546048;                // 1048576
static const size_t OFF_Y0   = 77594624;                // 33554432 (Ip aliases)
static const size_t OFF_X1   = 111149056;               // 33554432 (cand aliases)
static const size_t OFF_W0B  = 144703488;               // 262144
static const size_t OFF_W1B  = 144965632;               // 131072
static const size_t OFF_SC0  = 145096704;               // 1024
static const size_t OFF_SH0  = OFF_SC0 + 1024;
static const size_t OFF_SC1  = OFF_SH0 + 1024;
static const size_t OFF_SH1  = OFF_SC1 + 1024;

extern "C" void kernel_launch(void* const* d_in, const int* in_sizes, int n_in,
                              void* d_out, int out_size, void* d_ws, size_t ws_size,
                              hipStream_t stream) {
  const float* xyz1    = (const float*)d_in[0];
  const float* xyz2    = (const float*)d_in[1];
  const float* points1 = (const float*)d_in[2];
  const float* points2 = (const float*)d_in[3];
  const float* W0      = (const float*)d_in[4];
  // d_in[5] = b0 (cancels exactly inside BatchNorm; skipped)
  const float* W1      = (const float*)d_in[6];
  // d_in[7] = b1 (cancels)
  const float* g0      = (const float*)d_in[8];
  const float* be0     = (const float*)d_in[9];
  const float* g1      = (const float*)d_in[10];
  const float* be1     = (const float*)d_in[11];

  char* ws = (char*)d_ws;
  unsigned short* xcat = (unsigned short*)(ws + OFF_XCAT);
  unsigned short* p2t  = (unsigned short*)(ws + OFF_P2T);
  int4*  ki  = (int4*)(ws + OFF_KI);
  float4* kw = (float4*)(ws + OFF_KW);
  unsigned short* y0  = (unsigned short*)(ws + OFF_Y0);
  unsigned short* y1  = (unsigned short*)(ws + OFF_XCAT);  // alias: xcat dead after GEMM0
  unsigned short* w0b = (unsigned short*)(ws + OFF_W0B);
  unsigned short* w1b = (unsigned short*)(ws + OFF_W1B);
  float* sc0 = (float*)(ws + OFF_SC0);
  float* sh0 = (float*)(ws + OFF_SH0);
  float* sc1 = (float*)(ws + OFF_SC1);
  float* sh1 = (float*)(ws + OFF_SH1);
  // aliases (regions dead at time of use):
  float4*  cand = (float4*)(ws + OFF_X1);   // live prep2 -> knn_merge
  ushort4* Ip   = (ushort4*)(ws + OFF_Y0);  // dead before gemm0 writes y0 (4 MB)
  float*   psq  = (float*)(ws + OFF_KI);    // ki dead after interp

  dim3 blk(256);

  prep2_kernel<<<dim3(11072), blk, 0, stream>>>(points1, points2, W0, W1, xyz2,
                                                xcat, p2t, w0b, w1b, cand);

  knn_split<<<dim3(N_ / 256, B_, SPLIT_), blk, 0, stream>>>(xyz1, cand, Ip);
  knn_merge<<<dim3(BN_TOT / 256), blk, 0, stream>>>(xyz1, cand, Ip, ki, kw);

  interp_kernel<<<dim3(BN_TOT / 4), blk, 0, stream>>>(p2t, ki, kw, xcat);

  gemm_bt<512, false><<<dim3(NBLK_), dim3(512), 0, stream>>>(
      xcat, w0b, nullptr, nullptr, y0, psq);
  stats_final<<<dim3(16), blk, 0, stream>>>(psq, g0, be0, sc0, sh0);

  gemm_bt<256, true><<<dim3(NBLK_), dim3(512), 0, stream>>>(
      y0, w1b, sc0, sh0, y1, psq);
  stats_final<<<dim3(16), blk, 0, stream>>>(psq, g1, be1, sc1, sh1);

  final_kernel<<<dim3(N_ / 32, 4, B_), blk, 0, stream>>>(y1, sc1, sh1, (float*)d_out);
}